// Round 5
// baseline (220.296 us; speedup 1.0000x reference)
//
#include <hip/hip_runtime.h>
#include <hip/hip_bf16.h>

#define BATCH  4096
#define UNITS  1024
#define CDIM   2048   // K = UNITS + IN_DIM
#define NDIM   4096   // 4 * UNITS (f, i, c, o)

typedef __attribute__((ext_vector_type(8))) short bf16x8;
typedef __attribute__((ext_vector_type(4))) float f32x4;

__device__ __forceinline__ void gload_lds16(const void* g, void* l) {
    __builtin_amdgcn_global_load_lds(
        (const __attribute__((address_space(1))) unsigned int*)g,
        (__attribute__((address_space(3))) unsigned int*)l, 16, 0, 0);
}

__device__ __forceinline__ float sigm(float x) { return 1.f / (1.f + __expf(-x)); }
__device__ __forceinline__ float tanh_fast(float x) { return 2.f / (1.f + __expf(-2.f * x)) - 1.f; }

// ---- prep: concat-cast x + transpose-cast-permute W, fully vectorized -------
// Blocks [0, 4096): x-cast, 8 elems/thread, b128 stores.
// Blocks [4096, 6144): W transpose via 64x64 LDS tile, b128 stores.
// Wt row layout (gate-interleaved, 128-periodic):
//   n(U,g) = (U>>5)*128 + ((U>>4)&1)*64 + g*16 + (U&15)
__global__ void prep(const float* __restrict__ h, const float* __restrict__ in,
                     const float* __restrict__ Wf, const float* __restrict__ Wi,
                     const float* __restrict__ Wc, const float* __restrict__ Wo,
                     __hip_bfloat16* __restrict__ x, __hip_bfloat16* __restrict__ Wt) {
    __shared__ float tile[64 * 65];
    int b = blockIdx.x, tid = threadIdx.x;
    if (b < 4096) {
        // concat(hidden, inputs) -> bf16 x [BATCH, CDIM], 8 floats per thread
        int t   = b * 256 + tid;
        int row = t >> 8;
        int c8  = (t & 255) * 8;
        const float* src = (c8 < UNITS) ? (h + (size_t)row * UNITS + c8)
                                        : (in + (size_t)row * UNITS + (c8 - UNITS));
        float4 v0 = *(const float4*)src;
        float4 v1 = *(const float4*)(src + 4);
        union { __hip_bfloat16 b[8]; bf16x8 v; } pk;
        pk.b[0] = __float2bfloat16(v0.x); pk.b[1] = __float2bfloat16(v0.y);
        pk.b[2] = __float2bfloat16(v0.z); pk.b[3] = __float2bfloat16(v0.w);
        pk.b[4] = __float2bfloat16(v1.x); pk.b[5] = __float2bfloat16(v1.y);
        pk.b[6] = __float2bfloat16(v1.z); pk.b[7] = __float2bfloat16(v1.w);
        *(bf16x8*)(x + (size_t)row * CDIM + c8) = pk.v;
    } else {
        // W_g[CDIM, UNITS] f32 -> Wt[n(U,g), k] bf16, 64k x 64u tile
        int idx = b - 4096;                       // 2048 blocks: 4g x 32ky x 16ux
        int g = idx >> 9, rest = idx & 511, ky = rest >> 4, ux = rest & 15;
        const float* W = (g == 0) ? Wf : (g == 1) ? Wi : (g == 2) ? Wc : Wo;
        int k0 = ky * 64, u0 = ux * 64;
        // read 64 rows x 64 cols, float4-coalesced
#pragma unroll
        for (int q = 0; q < 4; ++q) {
            int s = q * 256 + tid;                // 1024 float4 slots
            int row = s >> 4, c4 = s & 15;
            float4 v = *(const float4*)&W[(size_t)(k0 + row) * UNITS + u0 + c4 * 4];
            *(float4*)&tile[row * 65 + c4 * 4] = v;
        }
        __syncthreads();
        // write 64 u-rows x 64 k, 8 bf16 (b128) per slot, 8-lane coalesced
#pragma unroll
        for (int q = 0; q < 2; ++q) {
            int s = q * 256 + tid;                // 512 slots
            int u = s >> 3, kc = s & 7;
            int U = u0 + u;
            int n = ((U >> 5) << 7) + (((U >> 4) & 1) << 6) + (g << 4) + (U & 15);
            union { __hip_bfloat16 b[8]; bf16x8 v; } pk;
#pragma unroll
            for (int j = 0; j < 8; ++j)
                pk.b[j] = __float2bfloat16(tile[(kc * 8 + j) * 65 + u]);
            *(bf16x8*)(Wt + (size_t)n * CDIM + k0 + kc * 8) = pk.v;
        }
    }
}

// ---- flatmm fused GEMM + LSTM gates, AITER-style no-drain pipeline ----------
// Block 128m x 256n, 4 waves; wave = 128m x 64n (8i x 4j of 16x16x32 MFMA).
// A: global_load_lds, 2-ahead, 3-buffer LDS rotation, one raw s_barrier per kt,
//    manual s_waitcnt vmcnt(12) (A-stage only; B prefetch stays in flight).
// B: L2->VGPR, 1-ahead, alternating register sets (unroll-2, no copy).
__global__ __launch_bounds__(256, 2) void gemm_lstm(
    const __hip_bfloat16* __restrict__ A,    // [BATCH, CDIM] bf16
    const __hip_bfloat16* __restrict__ Bt,   // [NDIM, CDIM] bf16, gate-interleaved
    const float* __restrict__ b_f, const float* __restrict__ b_i,
    const float* __restrict__ b_c, const float* __restrict__ b_o,
    const float* __restrict__ cell,          // [BATCH, UNITS]
    float* __restrict__ out)                 // [2, BATCH, UNITS]: hidden, cell
{
    __shared__ short As[3][128 * 64];        // 3 x 16 KB rotating buffers
    const int K = CDIM;

    int bid = blockIdx.x;
    int nb  = (bid & 7) * 2 + ((bid >> 3) & 1);   // XCD swizzle
    int mb  = bid >> 4;
    int m0  = mb * 128, n0 = nb * 256;

    int tid  = threadIdx.x;
    int w    = tid >> 6, lane = tid & 63;
    int quad = lane >> 4, r16 = lane & 15;
    int wn   = w * 64;

    f32x4 acc[8][4];
#pragma unroll
    for (int i = 0; i < 8; ++i)
#pragma unroll
        for (int j = 0; j < 4; ++j) acc[i][j] = (f32x4){0.f, 0.f, 0.f, 0.f};

    const short* Ag = (const short*)A  + (size_t)m0 * K;
    const short* Bg = (const short*)Bt + (size_t)(n0 + wn + r16) * K + quad * 8;

    auto stageA = [&](short* dst, int k0) {
#pragma unroll
        for (int q = 0; q < 4; ++q) {
            int s    = q * 256 + tid;          // 1024 slots of 16B = 128 rows x 8 chunks
            int row  = s >> 3;
            int cg   = (s & 7) ^ (row & 7);    // conflict-free xor8 swizzle
            int lofs = (q * 256 + w * 64) * 8; // wave-uniform LDS base (shorts)
            gload_lds16(Ag + (size_t)row * K + k0 + cg * 8, dst + lofs);
        }
    };
    auto loadB = [&](bf16x8* dst, int k0) {
#pragma unroll
        for (int ks = 0; ks < 2; ++ks)
#pragma unroll
            for (int j = 0; j < 4; ++j)
                dst[ks * 4 + j] = *(const bf16x8*)&Bg[(size_t)(j * 16) * K + k0 + ks * 32];
    };
    auto compute = [&](const short* pA, const bf16x8* B) {
#pragma unroll
        for (int ks = 0; ks < 2; ++ks) {
            bf16x8 af[8];
            int kc = ((quad + ks * 4) ^ (r16 & 7)) * 8;
#pragma unroll
            for (int i = 0; i < 8; ++i)
                af[i] = *(const bf16x8*)&pA[(i * 16 + r16) * 64 + kc];
#pragma unroll
            for (int i = 0; i < 8; ++i)
#pragma unroll
                for (int j = 0; j < 4; ++j)
                    acc[i][j] = __builtin_amdgcn_mfma_f32_16x16x32_bf16(af[i], B[ks * 4 + j], acc[i][j], 0, 0, 0);
        }
    };

    short *p0 = As[0], *p1 = As[1], *p2 = As[2];
    bf16x8 B0[8], B1[8];
    stageA(p0, 0);                             // A(0)
    stageA(p1, 64);                            // A(1)
    loadB(B0, 0);                              // B(0)

    // In-flight at each phase top: A(kt)[oldest 4] + A(kt+1)[4] + B(kt)[8].
    // vmcnt(12) waits only A(kt); barrier carries B + next-A across.
    // Tail issues are clamped to the last valid tile (data staged, never read).
    for (int kt = 0; kt < K / 64; kt += 2) {
        asm volatile("s_waitcnt vmcnt(12)" ::: "memory");
        asm volatile("s_barrier" ::: "memory");
        stageA(p2, min((kt + 2) * 64, K - 64));
        loadB(B1, min((kt + 1) * 64, K - 64));
        compute(p0, B0);
        { short* t = p0; p0 = p1; p1 = p2; p2 = t; }

        asm volatile("s_waitcnt vmcnt(12)" ::: "memory");
        asm volatile("s_barrier" ::: "memory");
        stageA(p2, min((kt + 3) * 64, K - 64));
        loadB(B0, min((kt + 2) * 64, K - 64));
        compute(p0, B1);
        { short* t = p0; p0 = p1; p1 = p2; p2 = t; }
    }

    // ---- fused LSTM epilogue: j = gate, u = nb*64 + (w>>1)*32 + (w&1)*16 + r16
    // C/D layout: col=lane&15, row=quad*4+reg (m89-verified)
    int u = nb * 64 + (w >> 1) * 32 + (w & 1) * 16 + r16;
    float bfv = b_f[u], biv = b_i[u], bcv = b_c[u], bov = b_o[u];
    float* out_h = out;
    float* out_c = out + (size_t)BATCH * UNITS;
#pragma unroll
    for (int i = 0; i < 8; ++i) {
#pragma unroll
        for (int rr = 0; rr < 4; ++rr) {
            int m = m0 + i * 16 + quad * 4 + rr;
            float fg = sigm(acc[i][0][rr] + bfv);
            float ig = sigm(acc[i][1][rr] + biv);
            float cc = tanh_fast(acc[i][2][rr] + bcv);
            float og = sigm(acc[i][3][rr] + bov);
            float cold = cell[(size_t)m * UNITS + u];
            float cn = fg * cold + ig * cc;
            out_h[(size_t)m * UNITS + u] = og * tanh_fast(cn);
            out_c[(size_t)m * UNITS + u] = cn;
        }
    }
}

extern "C" void kernel_launch(void* const* d_in, const int* in_sizes, int n_in,
                              void* d_out, int out_size, void* d_ws, size_t ws_size,
                              hipStream_t stream) {
    const float* inputs = (const float*)d_in[0];
    const float* hidden = (const float*)d_in[1];
    const float* cell   = (const float*)d_in[2];
    const float* Wf = (const float*)d_in[3];
    const float* bf_ = (const float*)d_in[4];
    const float* Wi = (const float*)d_in[5];
    const float* bi_ = (const float*)d_in[6];
    const float* Wc = (const float*)d_in[7];
    const float* bc_ = (const float*)d_in[8];
    const float* Wo = (const float*)d_in[9];
    const float* bo_ = (const float*)d_in[10];
    float* out = (float*)d_out;

    char* ws = (char*)d_ws;
    __hip_bfloat16* x  = (__hip_bfloat16*)ws;                  // 16 MB
    __hip_bfloat16* Wt = (__hip_bfloat16*)(ws + (16u << 20));  // 16 MB

    // 1) vectorized concat-cast x (4096 blocks) + W transpose-cast (2048 blocks)
    prep<<<dim3(6144), dim3(256), 0, stream>>>(hidden, inputs, Wf, Wi, Wc, Wo, x, Wt);
    // 2) flatmm fused 4-gate GEMM + LSTM gates, no-drain pipeline (512 blocks)
    gemm_lstm<<<dim3(512), dim3(256), 0, stream>>>(
        x, Wt, bf_, bi_, bc_, bo_, cell, out);
}